// Round 7
// baseline (948.228 us; speedup 1.0000x reference)
//
#include <hip/hip_runtime.h>
#include <cstdint>

// ---------------------------------------------------------------------------
// ChartParser: span scores + per-batch CKY DP + backtrack.
// B=64, S=256, D=H=1024. Output: int32 [2][B][S] (lefts then rights).
// Round 15 (GEMM1 only; cky/GEMM2/gemmnt unchanged from round 14):
//  - splitx: X pre-split once to fp16 limb planes (in tmpA region, dead
//    until GEMM2 overwrites it).
//  - gemm_ar (GEMM1): A fragments loaded DIRECTLY global->VGPR (8 contig
//    fp16 = 16B per fragment), register-double-buffered one K-step ahead;
//    LDS holds only the B double-buffer (32KB; global_load_lds w=16 with
//    pre-swizzled source). ONE barrier per K-step (per-wave vmcnt(0)+
//    lgkmcnt(0) before s_barrier covers B dbuf RAW and WAR). 3 blocks/CU
//    kept (round-13 lesson: occupancy cut masked the staging win).
//    Numerically bit-identical (same limbs, same product order).
// ---------------------------------------------------------------------------

#define Bb 64
#define Ss 256
#define Dd 1024
#define Hh 1024

typedef __attribute__((ext_vector_type(8))) _Float16 f16x8;
typedef __attribute__((ext_vector_type(4))) float f32x4;

// x = h + l + delta, |delta| <= 2^-22 |x| (fp16 RNE twice)
__device__ __forceinline__ void split2(float x, unsigned short& h,
                                       unsigned short& l) {
  _Float16 hh = (_Float16)x;
  _Float16 ll = (_Float16)(x - (float)hh);
  h = __builtin_bit_cast(unsigned short, hh);
  l = __builtin_bit_cast(unsigned short, ll);
}

// async global->LDS, 16B per lane; LDS dest = uniform base + lane*16
__device__ __forceinline__ void gl_lds16(const void* g, void* l) {
  __builtin_amdgcn_global_load_lds(
      (const __attribute__((address_space(1))) void*)g,
      (__attribute__((address_space(3))) void*)l, 16, 0, 0);
}

// ---------------------------------------------------------------------------
// Weight split+transpose: W fp32 [1024 k-rows, ld ldw] -> O fp16 [n][k],
// limb planes at +0, +plane.
// ---------------------------------------------------------------------------
__global__ __launch_bounds__(256) void splitw_kernel(
    const float* __restrict__ W, int ldw, unsigned short* __restrict__ O,
    long long plane) {
  int idx = blockIdx.x * 256 + threadIdx.x;  // n*1024 + k
  int n = idx >> 10, k = idx & 1023;
  float x = W[(long long)k * ldw + n];
  unsigned short h, l;
  split2(x, h, l);
  O[idx] = h;
  O[plane + idx] = l;
}

// X split, no transpose: X fp32 [16M] -> O fp16 planes [16M] h, l.
__global__ __launch_bounds__(256) void splitx_kernel(
    const float* __restrict__ X, unsigned short* __restrict__ O,
    long long plane) {
  long long i4 = ((long long)blockIdx.x * 256 + threadIdx.x) * 4;
  float4 v = *(const float4*)(X + i4);
  unsigned short h[4], l[4];
  split2(v.x, h[0], l[0]);
  split2(v.y, h[1], l[1]);
  split2(v.z, h[2], l[2]);
  split2(v.w, h[3], l[3]);
  uint2 hp, lp;
  hp.x = (unsigned)h[0] | ((unsigned)h[1] << 16);
  hp.y = (unsigned)h[2] | ((unsigned)h[3] << 16);
  lp.x = (unsigned)l[0] | ((unsigned)l[1] << 16);
  lp.y = (unsigned)l[2] | ((unsigned)l[3] << 16);
  *(uint2*)(O + i4) = hp;
  *(uint2*)(O + plane + i4) = lp;
}

// Extract Wbil's bias row / col / corner.
__global__ __launch_bounds__(256) void bilvec_kernel(
    const float* __restrict__ Wbil, float* __restrict__ brow,
    float* __restrict__ bcol, float* __restrict__ corner) {
  int i = blockIdx.x * 256 + threadIdx.x;  // 0..1023
  brow[i] = Wbil[1024 * 1025 + i];
  bcol[i] = Wbil[i * 1025 + 1024];
  if (i == 0) corner[0] = Wbil[1024 * 1025 + 1024];
}

__device__ __forceinline__ void pack8(char* dst, const unsigned short* v) {
  uint4 u;
  u.x = (unsigned)v[0] | ((unsigned)v[1] << 16);
  u.y = (unsigned)v[2] | ((unsigned)v[3] << 16);
  u.z = (unsigned)v[4] | ((unsigned)v[5] << 16);
  u.w = (unsigned)v[6] | ((unsigned)v[7] << 16);
  *(uint4*)dst = u;
}

// split 16 fp32 -> 2x16 fp16 limbs, store (swizzled) to 2 LDS planes
__device__ __forceinline__ void split_store16f(const float* xs, char* lds,
                                               int base, int wa0, int wa1) {
  unsigned short hs[16], ls[16];
#pragma unroll
  for (int i = 0; i < 16; ++i) split2(xs[i], hs[i], ls[i]);
  pack8(&lds[base + wa0], hs);
  pack8(&lds[base + wa1], hs + 8);
  pack8(&lds[base + 8192 + wa0], ls);
  pack8(&lds[base + 8192 + wa1], ls + 8);
}

// 4-product accumulate for one nf column: (ah+al)x(bh+bl), all kept
#define MFMA4(afv, bh, blv, accs, nf)                                        \
  {                                                                          \
    _Pragma("unroll") for (int mf = 0; mf < 4; ++mf) accs[mf][nf] =          \
        __builtin_amdgcn_mfma_f32_16x16x32_f16(afv[0][mf], bh,               \
                                               accs[mf][nf], 0, 0, 0);       \
    _Pragma("unroll") for (int mf = 0; mf < 4; ++mf) accs[mf][nf] =          \
        __builtin_amdgcn_mfma_f32_16x16x32_f16(afv[0][mf], blv,              \
                                               accs[mf][nf], 0, 0, 0);       \
    _Pragma("unroll") for (int mf = 0; mf < 4; ++mf) accs[mf][nf] =          \
        __builtin_amdgcn_mfma_f32_16x16x32_f16(afv[1][mf], bh,               \
                                               accs[mf][nf], 0, 0, 0);       \
    _Pragma("unroll") for (int mf = 0; mf < 4; ++mf) accs[mf][nf] =          \
        __builtin_amdgcn_mfma_f32_16x16x32_f16(afv[1][mf], blv,              \
                                               accs[mf][nf], 0, 0, 0);       \
  }

// ---------------------------------------------------------------------------
// GEMM1 (NN, A and B pre-split fp16): out = act(Asp * Bsp + bias).
// A fragments global->VGPR (reg-dbuf, prefetch 1 K-step); B via
// global_load_lds w=16 pre-swizzled source, LDS dbuf 2x16KB. One barrier
// per K-step. Tile 128x128, BK=32, 256 threads, wave-tile 64x64.
// If n0 >= 1024 the block writes C1/bias1 at col-1024 (fused dual output).
// ---------------------------------------------------------------------------
template <bool LEAKY>
__global__ __launch_bounds__(256, 3) void gemm_ar_kernel(
    const unsigned short* __restrict__ Asp, long long aplane,
    const unsigned short* __restrict__ Bsp, long long bplane,
    float* __restrict__ C0, float* __restrict__ C1,
    const float* __restrict__ bias0, const float* __restrict__ bias1) {
  const int m0 = blockIdx.y * 128;
  const int n0 = blockIdx.x * 128;
  __shared__ __align__(16) char lds[32768];  // B dbuf only
  const int t = threadIdx.x;
  const int L = t & 63, w = t >> 6, q = L >> 4, l15 = L & 15;

  int offB0[4];
#pragma unroll
  for (int f = 0; f < 4; ++f) {
    int rowb = ((w >> 1) << 6) + (f << 4) + l15;
    offB0[f] = rowb * 64 + ((q ^ (((rowb >> 1) ^ (rowb >> 3)) & 3)) << 4);
  }

  // A fragment sources: af[s][f] = Asp[s][(m0+rowa)*1024 + k0 + q*8]
  const unsigned short* aps[2][4];
#pragma unroll
  for (int f = 0; f < 4; ++f) {
    int rowa = ((w & 1) << 6) + (f << 4) + l15;
#pragma unroll
    for (int s = 0; s < 2; ++s)
      aps[s][f] = Asp + (long long)s * aplane +
                  (long long)(m0 + rowa) * 1024 + q * 8;
  }

  // B DMA sources: wave w issues 4 x 1KB; lane covers (row base+lane/4,
  // chunk c = lane&3); source k-chunk = c ^ phi(row); LDS dest linear.
  const int lrow = L >> 2, lchk = L & 3;
  const unsigned short* bsrc[4];
  int bldso[4];
#pragma unroll
  for (int i = 0; i < 4; ++i) {
    int O = ((w << 2) + i) << 10;
    int s2 = O >> 13;
    int r = ((O & 8191) >> 6) + lrow;
    int phi = ((r >> 1) ^ (r >> 3)) & 3;
    bsrc[i] = Bsp + (long long)s2 * bplane + (long long)(n0 + r) * 1024 +
              ((lchk ^ phi) << 3);
    bldso[i] = O;
  }

  f32x4 acc[4][4];
#pragma unroll
  for (int i = 0; i < 4; ++i)
#pragma unroll
    for (int j = 0; j < 4; ++j) acc[i][j] = (f32x4){0.f, 0.f, 0.f, 0.f};

  // prologue: B DMA (k0=0) into buf0; A regs k0=0
#pragma unroll
  for (int i = 0; i < 4; ++i) gl_lds16(bsrc[i], &lds[bldso[i]]);
  f16x8 af[2][4], afn[2][4];
#pragma unroll
  for (int s = 0; s < 2; ++s)
#pragma unroll
    for (int f = 0; f < 4; ++f) af[s][f] = *(const f16x8*)(aps[s][f]);
  asm volatile("s_waitcnt vmcnt(0)\n\ts_barrier" ::: "memory");

  int cur = 0;
  for (int k0 = 0; k0 < 1024; k0 += 32) {
    if (k0 < 992) {
      const int bn = (cur ^ 1) << 14;
#pragma unroll
      for (int i = 0; i < 4; ++i)
        gl_lds16(bsrc[i] + k0 + 32, &lds[bn + bldso[i]]);
#pragma unroll
      for (int s = 0; s < 2; ++s)
#pragma unroll
        for (int f = 0; f < 4; ++f)
          afn[s][f] = *(const f16x8*)(aps[s][f] + k0 + 32);
    }
    const int bbase = cur << 14;
#pragma unroll
    for (int nf = 0; nf < 4; ++nf) {
      f16x8 bh = *(const f16x8*)&lds[bbase + offB0[nf]];
      f16x8 bl = *(const f16x8*)&lds[bbase + 8192 + offB0[nf]];
      MFMA4(af, bh, bl, acc, nf);
    }
    // single barrier: next B-DMA + A-reg loads landed; this step's ds_reads
    // done (WAR for the DMA issued after the barrier).
    asm volatile("s_waitcnt vmcnt(0) lgkmcnt(0)\n\ts_barrier" ::: "memory");
    if (k0 < 992) {
#pragma unroll
      for (int s = 0; s < 2; ++s)
#pragma unroll
        for (int f = 0; f < 4; ++f) af[s][f] = afn[s][f];
    }
    cur ^= 1;
  }

  const bool isR = (n0 >= 1024);
  float* Co = isR ? C1 : C0;
  const float* bp = isR ? bias1 : bias0;
  const int nc0 = n0 & 1023;
#pragma unroll
  for (int nf = 0; nf < 4; ++nf) {
    int col = nc0 + ((w >> 1) << 6) + (nf << 4) + l15;
    float bz = bp[col];
#pragma unroll
    for (int mf = 0; mf < 4; ++mf) {
#pragma unroll
      for (int r = 0; r < 4; ++r) {
        int row = m0 + ((w & 1) << 6) + (mf << 4) + (q << 2) + r;
        float x = acc[mf][nf][r] + bz;
        if (LEAKY) x = (x > 0.f) ? x : 0.1f * x;
        Co[(long long)row * 1024 + col] = x;
      }
    }
  }
}

// ---------------------------------------------------------------------------
// MFMA GEMM (NN): out = act(A[M,1024]_fp32 * Bsp + bias). Round-12 version
// (GEMM2): B via DMA dbuf, A split in-kernel, 2 barriers/step, 3 blk/CU.
// ---------------------------------------------------------------------------
template <bool LEAKY>
__global__ __launch_bounds__(256, 3) void gemm_mfma_kernel(
    const float* __restrict__ A, const unsigned short* __restrict__ Bsp,
    long long bplane, float* __restrict__ C0, float* __restrict__ C1,
    const float* __restrict__ bias0, const float* __restrict__ bias1) {
  const int m0 = blockIdx.y * 128;
  const int n0 = blockIdx.x * 128;
  __shared__ __align__(16) char lds[49152];
  const int t = threadIdx.x;
  const int L = t & 63, w = t >> 6, q = L >> 4, l15 = L & 15;

  const int ar = t >> 1, ah = t & 1;
  const float* aptr = A + (long long)(m0 + ar) * 1024 + ah * 16;
  const int phiA = ((ar >> 1) ^ (ar >> 3)) & 3;
  const int wa0 = ar * 64 + (((2 * ah + 0) ^ phiA) << 4);
  const int wa1 = ar * 64 + (((2 * ah + 1) ^ phiA) << 4);

  int offA0[4], offB0[4];
#pragma unroll
  for (int f = 0; f < 4; ++f) {
    int rowa = ((w & 1) << 6) + (f << 4) + l15;
    offA0[f] = rowa * 64 + ((q ^ (((rowa >> 1) ^ (rowa >> 3)) & 3)) << 4);
    int rowb = ((w >> 1) << 6) + (f << 4) + l15;
    offB0[f] = rowb * 64 + ((q ^ (((rowb >> 1) ^ (rowb >> 3)) & 3)) << 4);
  }

  const int lrow = L >> 2, lchk = L & 3;
  const unsigned short* bsrc[4];
  int bldso[4];
#pragma unroll
  for (int i = 0; i < 4; ++i) {
    int O = ((w << 2) + i) << 10;
    int s2 = O >> 13;
    int r = ((O & 8191) >> 6) + lrow;
    int phi = ((r >> 1) ^ (r >> 3)) & 3;
    bsrc[i] = Bsp + (long long)s2 * bplane + (long long)(n0 + r) * 1024 +
              ((lchk ^ phi) << 3);
    bldso[i] = O;
  }

  f32x4 acc[4][4];
#pragma unroll
  for (int i = 0; i < 4; ++i)
#pragma unroll
    for (int j = 0; j < 4; ++j) acc[i][j] = (f32x4){0.f, 0.f, 0.f, 0.f};

#pragma unroll
  for (int i = 0; i < 4; ++i) gl_lds16(bsrc[i], &lds[16384 + bldso[i]]);
  float4 a0 = *(const float4*)(aptr + 0);
  float4 a1 = *(const float4*)(aptr + 4);
  float4 a2 = *(const float4*)(aptr + 8);
  float4 a3 = *(const float4*)(aptr + 12);

  int cur = 0;
  for (int k0 = 0; k0 < 1024; k0 += 32) {
    {
      float xs[16] = {a0.x, a0.y, a0.z, a0.w, a1.x, a1.y, a1.z, a1.w,
                      a2.x, a2.y, a2.z, a2.w, a3.x, a3.y, a3.z, a3.w};
      split_store16f(xs, lds, 0, wa0, wa1);
    }
    asm volatile("s_waitcnt vmcnt(0) lgkmcnt(0)\n\ts_barrier" ::: "memory");
    if (k0 < 992) {
      a0 = *(const float4*)(aptr + k0 + 32);
      a1 = *(const float4*)(aptr + k0 + 36);
      a2 = *(const float4*)(aptr + k0 + 40);
      a3 = *(const float4*)(aptr + k0 + 44);
      const int bn = 16384 + ((cur ^ 1) << 14);
#pragma unroll
      for (int i = 0; i < 4; ++i)
        gl_lds16(bsrc[i] + k0 + 32, &lds[bn + bldso[i]]);
    }
    const int bb = 16384 + (cur << 14);
    f16x8 af[2][4];
#pragma unroll
    for (int s = 0; s < 2; ++s)
#pragma unroll
      for (int f = 0; f < 4; ++f)
        af[s][f] = *(const f16x8*)&lds[s * 8192 + offA0[f]];
#pragma unroll
    for (int nf = 0; nf < 4; ++nf) {
      f16x8 bh = *(const f16x8*)&lds[bb + offB0[nf]];
      f16x8 bl = *(const f16x8*)&lds[bb + 8192 + offB0[nf]];
      MFMA4(af, bh, bl, acc, nf);
    }
    asm volatile("s_waitcnt lgkmcnt(0)\n\ts_barrier" ::: "memory");
    cur ^= 1;
  }

  const bool isR = (n0 >= 1024);
  float* Co = isR ? C1 : C0;
  const float* bp = isR ? bias1 : bias0;
  const int nc0 = n0 & 1023;
#pragma unroll
  for (int nf = 0; nf < 4; ++nf) {
    int col = nc0 + ((w >> 1) << 6) + (nf << 4) + l15;
    float bz = bp[col];
#pragma unroll
    for (int mf = 0; mf < 4; ++mf) {
#pragma unroll
      for (int r = 0; r < 4; ++r) {
        int row = m0 + ((w & 1) << 6) + (mf << 4) + (q << 2) + r;
        float x = acc[mf][nf][r] + bz;
        if (LEAKY) x = (x > 0.f) ? x : 0.1f * x;
        Co[(long long)row * 1024 + col] = x;
      }
    }
  }
}

// ---------------------------------------------------------------------------
// Batched NT GEMM on MFMA: C[b] = tmpA[b] * rights[b]^T + rowAdd + scal.
// Both operands fp32, split in-kernel to fp16x2. Tile 128x128, grid (2,2,64).
// ---------------------------------------------------------------------------
__global__ __launch_bounds__(256, 3) void gemmnt_mfma_kernel(
    const float* __restrict__ A, const float* __restrict__ B,
    float* __restrict__ C, const float* __restrict__ rowAdd,
    const float* __restrict__ scal) {
  const int bz = blockIdx.z;
  A += (long long)bz * 256 * 1024;
  B += (long long)bz * 256 * 1024;
  C += (long long)bz * 256 * 256;
  const int m0 = blockIdx.y * 128;
  const int n0 = blockIdx.x * 128;
  __shared__ __align__(16) char lds[32768];
  const int t = threadIdx.x;
  const int L = t & 63, w = t >> 6, q = L >> 4, l15 = L & 15;

  const int ar = t >> 1, ah = t & 1;
  const float* aptr = A + (long long)(m0 + ar) * 1024 + ah * 16;
  const float* bptr = B + (long long)(n0 + ar) * 1024 + ah * 16;
  const int phiA = ((ar >> 1) ^ (ar >> 3)) & 3;
  const int wa0 = ar * 64 + (((2 * ah + 0) ^ phiA) << 4);
  const int wa1 = ar * 64 + (((2 * ah + 1) ^ phiA) << 4);

  int offA0[4], offB0[4];
#pragma unroll
  for (int f = 0; f < 4; ++f) {
    int rowa = ((w & 1) << 6) + (f << 4) + l15;
    offA0[f] = rowa * 64 + ((q ^ (((rowa >> 1) ^ (rowa >> 3)) & 3)) << 4);
    int rowb = ((w >> 1) << 6) + (f << 4) + l15;
    offB0[f] =
        16384 + rowb * 64 + ((q ^ (((rowb >> 1) ^ (rowb >> 3)) & 3)) << 4);
  }

  f32x4 acc[4][4];
#pragma unroll
  for (int i = 0; i < 4; ++i)
#pragma unroll
    for (int j = 0; j < 4; ++j) acc[i][j] = (f32x4){0.f, 0.f, 0.f, 0.f};

  float4 a0 = *(const float4*)(aptr + 0);
  float4 a1 = *(const float4*)(aptr + 4);
  float4 a2 = *(const float4*)(aptr + 8);
  float4 a3 = *(const float4*)(aptr + 12);
  float4 b0 = *(const float4*)(bptr + 0);
  float4 b1 = *(const float4*)(bptr + 4);
  float4 b2 = *(const float4*)(bptr + 8);
  float4 b3 = *(const float4*)(bptr + 12);

  for (int k0 = 0; k0 < 1024; k0 += 32) {
    {
      float xs[16] = {a0.x, a0.y, a0.z, a0.w, a1.x, a1.y, a1.z, a1.w,
                      a2.x, a2.y, a2.z, a2.w, a3.x, a3.y, a3.z, a3.w};
      split_store16f(xs, lds, 0, wa0, wa1);
      float ys[16] = {b0.x, b0.y, b0.z, b0.w, b1.x, b1.y, b1.z, b1.w,
                      b2.x, b2.y, b2.z, b2.w, b3.x, b3.y, b3.z, b3.w};
      split_store16f(ys, lds, 16384, wa0, wa1);
    }
    asm volatile("s_waitcnt lgkmcnt(0)\n\ts_barrier" ::: "memory");
    if (k0 < 992) {
      a0 = *(const float4*)(aptr + k0 + 32);
      a1 = *(const float4*)(aptr + k0 + 36);
      a2 = *(const float4*)(aptr + k0 + 40);
      a3 = *(const float4*)(aptr + k0 + 44);
      b0 = *(const float4*)(bptr + k0 + 32);
      b1 = *(const float4*)(bptr + k0 + 36);
      b2 = *(const float4*)(bptr + k0 + 40);
      b3 = *(const float4*)(bptr + k0 + 44);
    }
    f16x8 af[2][4];
#pragma unroll
    for (int s = 0; s < 2; ++s)
#pragma unroll
      for (int f = 0; f < 4; ++f)
        af[s][f] = *(const f16x8*)&lds[s * 8192 + offA0[f]];
#pragma unroll
    for (int nf = 0; nf < 4; ++nf) {
      f16x8 bh = *(const f16x8*)&lds[offB0[nf]];
      f16x8 bl = *(const f16x8*)&lds[8192 + offB0[nf]];
      MFMA4(af, bh, bl, acc, nf);
    }
    asm volatile("s_waitcnt lgkmcnt(0)\n\ts_barrier" ::: "memory");
  }

  const float sc_add = scal[0];
#pragma unroll
  for (int mf = 0; mf < 4; ++mf) {
#pragma unroll
    for (int r = 0; r < 4; ++r) {
      int row = m0 + ((w & 1) << 6) + (mf << 4) + (q << 2) + r;
      float radd = sc_add + rowAdd[(long long)bz * 256 + row];
#pragma unroll
      for (int nf = 0; nf < 4; ++nf) {
        int col = n0 + ((w >> 1) << 6) + (nf << 4) + l15;
        C[(long long)row * 256 + col] = acc[mf][nf][r] + radd;
      }
    }
  }
}

// ---------------------------------------------------------------------------
// tmpb[i] = dot(lefts[i,:], Wbil[0:H, H]) + Wbil[H,H].  One wave per row.
// ---------------------------------------------------------------------------
__global__ __launch_bounds__(64) void colvec_kernel(
    const float* __restrict__ lefts, const float* __restrict__ bcol,
    const float* __restrict__ corner, float* __restrict__ tmpb) {
  int row = blockIdx.x;
  int lane = threadIdx.x;
  const float* a = lefts + (long long)row * Hh;
  float s = 0.f;
#pragma unroll
  for (int h = lane; h < Hh; h += 64) s = fmaf(a[h], bcol[h], s);
#pragma unroll
  for (int off = 32; off > 0; off >>= 1) s += __shfl_down(s, off, 64);
  if (lane == 0) tmpb[row] = s + corner[0];
}

// ---------------------------------------------------------------------------
// CKY + backtrack. One block per batch, 1024 threads. Chart in LDS, packed
// triangular diag-major. EIGHT diagonals per barrier (round 14, unchanged).
// ---------------------------------------------------------------------------
__global__ __launch_bounds__(1024) void cky_kernel(
    const float* __restrict__ scores,  // [64][256][256]
    uint8_t* __restrict__ Sws,         // [64][32896] packed triangular
    int* __restrict__ out)             // [2][64][256] int32
{
  const int b = blockIdx.x;
  const int t = threadIdx.x;
  const int n = Ss;
  const float* sc = scores + (long long)b * n * n;
  uint8_t* SP = Sws + (long long)b * 32896;

  __shared__ float Dch[32896];
  __shared__ float pv[2][2048];
  __shared__ uint8_t pmv[2][2048];
  __shared__ int stk[256];

  // offsets of tiny diags 0..15
  const int offT[16] = {0,    256,  511,  765,  1018, 1270, 1521, 1771,
                        2020, 2268, 2515, 2761, 3006, 3250, 3493, 3735};

  if (t < n) {
    out[b * n + t] = 0;
    out[Bb * n + b * n + t] = 0;
    Dch[t] = 0.f;  // diag 0
  }
  // s=2 reads pv[1]: its partial range is empty -> -inf sentinel
  pv[1][t] = -3.0e38f;
  pv[1][t + 1024] = -3.0e38f;

  // prologue score prefetch (diags 1..15 at cell t, clamped addresses)
  float PS[16];
  PS[0] = 0.f;
#pragma unroll
  for (int w = 1; w <= 15; ++w) {
    int ic = t;
    if (ic > 255 - w) ic = 255 - w;
    PS[w] = sc[ic * 257 + w];
  }
  asm volatile("s_waitcnt lgkmcnt(0)\n\ts_barrier" ::: "memory");

  // prologue: diags 1..15, one barrier each (generic ascending m-scan,
  // strict > = first-max)
#pragma unroll
  for (int w = 1; w <= 15; ++w) {
    if (t < 256 - w) {
      float bb = Dch[offT[w - 1] + t + 1];  // m=0: 0 + right
      int bm = 0;
#pragma unroll
      for (int m = 1; m < 15; ++m) {
        if (m >= w) break;
        float c = Dch[offT[m] + t] + Dch[offT[w - 1 - m] + t + m + 1];
        if (c > bb) { bb = c; bm = m; }
      }
      Dch[offT[w] + t] = PS[w] + bb;
      SP[offT[w] + t] = (uint8_t)bm;
    }
    asm volatile("s_waitcnt lgkmcnt(0)\n\ts_barrier" ::: "memory");
  }

  // (b): partials for superstep s+1 (8 diags, base W0b+8).
  // Covers m in [jb+8, W0b-1]; all spans are diags <= W0b-1 (>= 1 barrier
  // old when consumed). Slot = jb*256 + cell (RA) or jb*256+gb*128+cell.
  auto run_b = [&](int W0b, int pbuf) {
    const int cnv = n - W0b - 8;  // consumer's nv1
    int jb, gb, u, delta;
    if (cnv > 128) {  // RA: T=128, 1 group/diag, slices (u, u+128)
      jb = 7 - (t >> 7);
      gb = 0;
      u = t & 127;
      delta = 128;
    } else {  // RB/RC: T=64, 2 groups/diag
      const int wid = t >> 6;
      jb = 7 - (wid >> 1);
      gb = wid & 1;
      u = t & 63;
      delta = (cnv > 64) ? 64 : 0;
    }
    const int Wb = W0b + 8 + jb;
    const int nvb = n - Wb;
    int cnt = W0b - jb - 8;
    if (cnt < 0) cnt = 0;
    const int mlo = jb + 8;
    int ml, mh;
    if (cnv > 128) {
      ml = mlo;
      mh = mlo + cnt;
    } else {
      const int per = (cnt + 1) >> 1;
      ml = mlo + gb * per;
      mh = mlo + cnt;
      int e = ml + per;
      if (e < mh) mh = e;
    }
    float b0 = -3.0e38f, b1 = -3.0e38f;
    int m0i = ml, m1i = ml;
    if (u < nvb && ml < mh) {
      int al = ml * n - ((ml * (ml - 1)) >> 1) + u;
      const int kr = Wb - 1 - ml;
      int ar = kr * n - ((kr * (kr - 1)) >> 1) + u + ml + 1;
      int dl = n - ml;
      int dr = n - Wb + ml + 1;
      if (delta) {
#pragma unroll 4
        for (int m = ml; m < mh; ++m) {
          float l0 = Dch[al], l1 = Dch[al + delta];  // -> ds_read2_b32
          float r0 = Dch[ar], r1 = Dch[ar + delta];  // -> ds_read2_b32
          float c0 = l0 + r0, c1 = l1 + r1;
          if (c0 > b0) { b0 = c0; m0i = m; }  // strict > = first max
          if (c1 > b1) { b1 = c1; m1i = m; }
          al += dl;
          ar -= dr;
          --dl;
          ++dr;
        }
      } else {
#pragma unroll 8
        for (int m = ml; m < mh; ++m) {
          float c = Dch[al] + Dch[ar];
          if (c > b0) { b0 = c; m0i = m; }
          al += dl;
          ar -= dr;
          --dl;
          ++dr;
        }
      }
    }
    const int slot = jb * 256 + gb * 128 + u;
    pv[pbuf][slot] = b0;
    pmv[pbuf][slot] = (uint8_t)m0i;
    if (delta) {
      pv[pbuf][slot + delta] = b1;
      pmv[pbuf][slot + delta] = (uint8_t)m1i;
    }
  };

  // (a)-band geometry: wave wv covers cells 57*wv + lane (7-lane overlap)
  const int wv = t >> 6, lane = t & 63;
  const int tcell = 57 * wv + lane;

  // seed scores for s=2 (diags 16..23)
  float scA[8];
#pragma unroll
  for (int j = 0; j < 8; ++j) {
    const int Wn = 16 + j;
    int ic = tcell;
    if (ic > 255 - Wn) ic = 255 - Wn;
    scA[j] = sc[ic * 257 + Wn];
  }

  for (int s = 2; s <= 31; ++s) {
    const int W0 = 8 * s;
    const int nv1 = n - W0;
    const int pb = s & 1, po = pb ^ 1;
    const int nb = (nv1 + 56) / 57;

    // prefetch next superstep's scores (diags W0+8..W0+15)
    float P8[8] = {0.f, 0.f, 0.f, 0.f, 0.f, 0.f, 0.f, 0.f};
    if (s < 31 && wv < nb) {
#pragma unroll
      for (int j = 0; j < 8; ++j) {
        const int Wn = W0 + 8 + j;
        int ic = tcell;
        if (ic > 255 - Wn) ic = 255 - Wn;
        if (ic < 0) ic = 0;
        P8[j] = sc[ic * 257 + Wn];
      }
    }

    // ---- (a): finalize diags W0..W0+7 ----
    if (wv < nb) {
      const int tc = (tcell < nv1) ? tcell : (nv1 - 1);  // clamped (safe)
      const float* pvo = pv[po];
      const uint8_t* pmo = pmv[po];
      const bool RA = (nv1 > 128);
      int offPB[8], offCB[8];
#pragma unroll
      for (int d = 0; d < 8; ++d) {
        const int dg = W0 - 8 + d;
        offPB[d] = dg * 256 - ((dg * (dg - 1)) >> 1);
        const int cg = W0 + d;
        offCB[d] = cg * 256 - ((cg * (cg - 1)) >> 1);
      }
      float VAL[8];
#pragma unroll
      for (int j = 0; j < 8; ++j) {
        const int W = W0 + j;
        float bb;
        int bm = 0;
        // m = 0
        if (j == 0) {
          bb = Dch[offPB[7] + tc + 1];  // 0 + prev-batch diag W0-1
        } else {
          bb = __shfl_down(VAL[j - 1], 1, 64);  // 0 + VAL_{j-1}(c+1)
        }
        // dyn-low m in [1, j-1]
#pragma unroll
        for (int m = 1; m < 8; ++m) {
          if (m >= j) break;
          float c = Dch[offT[m] + tc] + __shfl_down(VAL[j - 1 - m], m + 1, 64);
          if (c > bb) { bb = c; bm = m; }
        }
        // static-low m in [max(j,1), j+7]
#pragma unroll
        for (int m2 = 0; m2 < 8; ++m2) {
          const int m = j + m2;
          if (m == 0) continue;  // handled as m=0
          float c = Dch[offT[m] + tc] + Dch[offPB[7 - m2] + tc + m + 1];
          if (c > bb) { bb = c; bm = m; }
        }
        // partials [j+8, W0-9]
        if (RA) {
          const int sl = j * 256 + tc;
          float x = pvo[sl];
          if (x > bb) { bb = x; bm = pmo[sl]; }
        } else {
#pragma unroll
          for (int g = 0; g < 2; ++g) {
            const int sl = j * 256 + g * 128 + tc;
            float x = pvo[sl];
            if (x > bb) { bb = x; bm = pmo[sl]; }
          }
        }
        // static-high m = W0-8+d, d = 0..7 (ascending)
#pragma unroll
        for (int d = 0; d < 8; ++d) {
          const int m = W0 - 8 + d;
          const int rp = j + 7 - d;  // right tiny diag
          float right = (rp == 0) ? 0.f : Dch[offT[rp] + tc + W - rp];
          float c = Dch[offPB[d] + tc] + right;
          if (c > bb) { bb = c; bm = m; }
        }
        // dyn-high m = W0+e, e in [0, j-1]
#pragma unroll
        for (int e = 0; e < 8; ++e) {
          if (e >= j) break;
          const int rp = j - 1 - e;
          float right = (rp == 0) ? 0.f : Dch[offT[rp] + tc + W - rp];
          float c = VAL[e] + right;
          if (c > bb) { bb = c; bm = W0 + e; }
        }
        VAL[j] = scA[j] + bb;
        if (lane <= 63 - j && tcell < nv1 - j) {
          Dch[offCB[j] + tcell] = VAL[j];
          SP[offCB[j] + tcell] = (uint8_t)bm;
        }
      }
    }

    // ---- (b): partials for superstep s+1 (diags W0+8..W0+15) ----
    if (s < 31) run_b(W0, pb);

    asm volatile("s_waitcnt lgkmcnt(0)\n\ts_barrier" ::: "memory");
#pragma unroll
    for (int j = 0; j < 8; ++j) scA[j] = P8[j];
  }

  // Drain all SP stores (whole loop's worth) once, then barrier.
  asm volatile("s_waitcnt vmcnt(0) lgkmcnt(0)\n\ts_barrier" ::: "memory");
  uint8_t* spl = (uint8_t*)Dch;
  for (int idx = t; idx < 32896; idx += 1024) spl[idx] = SP[idx];
  asm volatile("s_waitcnt vmcnt(0) lgkmcnt(0)\n\ts_barrier" ::: "memory");
  if (t == 0) {
    int top = 0;
    stk[top++] = (0 << 16) | (n - 1);
    int cnt = 0;
    for (int step = 0; step < n - 1; ++step) {
      if (top > 0) {
        int ij = stk[--top];
        int ii = ij >> 16, jj = ij & 0xffff;
        out[b * n + cnt] = ii;
        out[Bb * n + b * n + cnt] = jj;
        ++cnt;
        int k = jj - ii;
        int s2 = ii + (int)spl[k * n - ((k * (k - 1)) >> 1) + ii];
        stk[top] = (ii << 16) | s2;
        if (s2 > ii) ++top;
        stk[top] = ((s2 + 1) << 16) | jj;
        if (jj > s2 + 1) ++top;
      }
    }
  }
}

// ---------------------------------------------------------------------------
// Launch
// ---------------------------------------------------------------------------
extern "C" void kernel_launch(void* const* d_in, const int* in_sizes, int n_in,
                              void* d_out, int out_size, void* d_ws,
                              size_t ws_size, hipStream_t stream) {
  const float* X = (const float*)d_in[0];     // [64,256,1024]
  const float* Wl = (const float*)d_in[2];    // [1024,1024]
  const float* bl = (const float*)d_in[3];    // [1024]
  const float* Wr = (const float*)d_in[4];
  const float* br = (const float*)d_in[5];
  const float* Wbil = (const float*)d_in[6];  // [1025,1025]
  const float* bbil = (const float*)d_in[7];  // scalar
  int* out = (int*)d_out;

  // workspace layout
  float* ws = (float*)d_ws;
  float* lefts = ws;                          // 16777216 f
  float* rights = lefts + 16777216;           // 16777216 f
  float* tmpA = rights + 16777216;            // 16777216 f
  float* scoresP = tmpA + 16777216;           // 4194304 f
  float* tmpb = scoresP + 4194304;            // 16384 f
  float* browp = tmpb + 16384;                // 1024 f
  float* bcolp = browp + 1024;                // 1024 f
  float* cornerp = bcolp + 1024;              // 4 f
  unsigned short* Wlrt = (unsigned short*)(cornerp + 4);  // 2 x 2M fp16
  unsigned short* Wct = Wlrt + 2LL * 2097152;             // 2 x 1M fp16
  uint8_t* SPp = (uint8_t*)(Wct + 2LL * 1048576);         // 64x32896 u8

  // X pre-split limb planes live in the tmpA region (dead until GEMM2's
  // output overwrites it; GEMM1 reads Xsp strictly before GEMM2 runs).
  unsigned short* Xsp = (unsigned short*)tmpA;

  // weight splits (+ Wbil bias vectors) + X split
  splitw_kernel<<<dim3(4096), 256, 0, stream>>>(Wl, 1024, Wlrt, 2097152);
  splitw_kernel<<<dim3(4096), 256, 0, stream>>>(Wr, 1024, Wlrt + 1048576,
                                                2097152);
  splitw_kernel<<<dim3(4096), 256, 0, stream>>>(Wbil, 1025, Wct, 1048576);
  bilvec_kernel<<<dim3(4), 256, 0, stream>>>(Wbil, browp, bcolp, cornerp);
  splitx_kernel<<<dim3(16384), 256, 0, stream>>>(X, Xsp, 16777216LL);

  // fused lefts|rights GEMM: N=2048, A in registers, 1 barrier/K-step
  dim3 gLR(16, 128);
  gemm_ar_kernel<true><<<gLR, 256, 0, stream>>>(
      Xsp, 16777216LL, Wlrt, 2097152LL, lefts, rights, bl, br);

  colvec_kernel<<<dim3(16384), 64, 0, stream>>>(lefts, bcolp, cornerp, tmpb);

  dim3 gA(8, 128);
  gemm_mfma_kernel<false><<<gA, 256, 0, stream>>>(lefts, Wct, 1048576LL, tmpA,
                                                  tmpA, browp, browp);

  dim3 g3(2, 2, 64);
  gemmnt_mfma_kernel<<<g3, 256, 0, stream>>>(tmpA, rights, scoresP, tmpb,
                                             bbil);

  cky_kernel<<<dim3(Bb), dim3(1024), 0, stream>>>(scoresP, SPp, out);
}

// Round 8
// 809.824 us; speedup vs baseline: 1.1709x; 1.1709x over previous
//
#include <hip/hip_runtime.h>
#include <cstdint>

// ---------------------------------------------------------------------------
// ChartParser: span scores + per-batch CKY DP + backtrack.
// B=64, S=256, D=H=1024. Output: int32 [2][B][S] (lefts then rights).
// Round 16 (base = round 14; round-15 gemm_ar reverted — 293MB overfetch):
//  - MFMA 4->3 products: drop al*bl (<=2^-44 relative, 22 bits below the
//    tolerated 2^-22 limb representation error). 25% fewer MFMA ops.
//  - splitw: coalesced via LDS 64x64 transpose tile (old version read W at
//    stride-4KB, uncoalesced).
//  - cky (8 diags/barrier), gemmnt, colvec unchanged.
// ---------------------------------------------------------------------------

#define Bb 64
#define Ss 256
#define Dd 1024
#define Hh 1024

typedef __attribute__((ext_vector_type(8))) _Float16 f16x8;
typedef __attribute__((ext_vector_type(4))) float f32x4;

// x = h + l + delta, |delta| <= 2^-22 |x| (fp16 RNE twice)
__device__ __forceinline__ void split2(float x, unsigned short& h,
                                       unsigned short& l) {
  _Float16 hh = (_Float16)x;
  _Float16 ll = (_Float16)(x - (float)hh);
  h = __builtin_bit_cast(unsigned short, hh);
  l = __builtin_bit_cast(unsigned short, ll);
}

// async global->LDS, 16B per lane; LDS dest = uniform base + lane*16
__device__ __forceinline__ void gl_lds16(const void* g, void* l) {
  __builtin_amdgcn_global_load_lds(
      (const __attribute__((address_space(1))) void*)g,
      (__attribute__((address_space(3))) void*)l, 16, 0, 0);
}

// ---------------------------------------------------------------------------
// Weight split+transpose (coalesced): W fp32 [1024 k-rows, ld ldw] ->
// O fp16 [n][k], limb planes at +0, +plane. 64x64 tile via LDS.
// ---------------------------------------------------------------------------
__global__ __launch_bounds__(256) void splitw_kernel(
    const float* __restrict__ W, int ldw, unsigned short* __restrict__ O,
    long long plane) {
  __shared__ float tile[64][65];
  const int k0 = blockIdx.x * 64;
  const int n0 = blockIdx.y * 64;
  const int i = threadIdx.x >> 6;  // 0..3
  const int j = threadIdx.x & 63;
#pragma unroll
  for (int r = 0; r < 16; ++r) {
    int k = k0 + (r << 2) + i;
    tile[j][(r << 2) + i] = W[(long long)k * ldw + n0 + j];  // coalesced in j
  }
  __syncthreads();
#pragma unroll
  for (int r = 0; r < 16; ++r) {
    int n = n0 + (r << 2) + i;
    float x = tile[(r << 2) + i][j];
    unsigned short h, l;
    split2(x, h, l);
    long long o = (long long)n * 1024 + k0 + j;  // coalesced in j
    O[o] = h;
    O[plane + o] = l;
  }
}

// Extract Wbil's bias row / col / corner.
__global__ __launch_bounds__(256) void bilvec_kernel(
    const float* __restrict__ Wbil, float* __restrict__ brow,
    float* __restrict__ bcol, float* __restrict__ corner) {
  int i = blockIdx.x * 256 + threadIdx.x;  // 0..1023
  brow[i] = Wbil[1024 * 1025 + i];
  bcol[i] = Wbil[i * 1025 + 1024];
  if (i == 0) corner[0] = Wbil[1024 * 1025 + 1024];
}

__device__ __forceinline__ void pack8(char* dst, const unsigned short* v) {
  uint4 u;
  u.x = (unsigned)v[0] | ((unsigned)v[1] << 16);
  u.y = (unsigned)v[2] | ((unsigned)v[3] << 16);
  u.z = (unsigned)v[4] | ((unsigned)v[5] << 16);
  u.w = (unsigned)v[6] | ((unsigned)v[7] << 16);
  *(uint4*)dst = u;
}

// split 16 fp32 -> 2x16 fp16 limbs, store (swizzled) to 2 LDS planes
__device__ __forceinline__ void split_store16f(const float* xs, char* lds,
                                               int base, int wa0, int wa1) {
  unsigned short hs[16], ls[16];
#pragma unroll
  for (int i = 0; i < 16; ++i) split2(xs[i], hs[i], ls[i]);
  pack8(&lds[base + wa0], hs);
  pack8(&lds[base + wa1], hs + 8);
  pack8(&lds[base + 8192 + wa0], ls);
  pack8(&lds[base + 8192 + wa1], ls + 8);
}

// 3-product accumulate for one nf column: ah*bh + ah*bl + al*bh
// (al*bl dropped: <=2^-44 relative, far below the 2^-22 limb error)
#define MFMA3(afv, bh, blv, accs, nf)                                        \
  {                                                                          \
    _Pragma("unroll") for (int mf = 0; mf < 4; ++mf) accs[mf][nf] =          \
        __builtin_amdgcn_mfma_f32_16x16x32_f16(afv[0][mf], bh,               \
                                               accs[mf][nf], 0, 0, 0);       \
    _Pragma("unroll") for (int mf = 0; mf < 4; ++mf) accs[mf][nf] =          \
        __builtin_amdgcn_mfma_f32_16x16x32_f16(afv[0][mf], blv,              \
                                               accs[mf][nf], 0, 0, 0);       \
    _Pragma("unroll") for (int mf = 0; mf < 4; ++mf) accs[mf][nf] =          \
        __builtin_amdgcn_mfma_f32_16x16x32_f16(afv[1][mf], bh,               \
                                               accs[mf][nf], 0, 0, 0);       \
  }

// ---------------------------------------------------------------------------
// MFMA GEMM (NN): out = act(A[M,1024]_fp32 * Bsp + bias). Bsp pre-split fp16
// [n][k], limb planes at stride bplane. Tile 128x128, BK=32, 256 threads,
// wave-tile 64x64. LDS 48KB: Ah@0, Al@8192, Bbuf0@16384, Bbuf1@32768.
// B via global_load_lds w=16 (pre-swizzled source), dbuf, issued 1 step
// ahead; A fp32 regs prefetched 1 step ahead, split in-kernel.
// If n0 >= 1024 the block writes C1/bias1 at col-1024 (fused dual output).
// ---------------------------------------------------------------------------
template <bool LEAKY>
__global__ __launch_bounds__(256, 3) void gemm_mfma_kernel(
    const float* __restrict__ A, const unsigned short* __restrict__ Bsp,
    long long bplane, float* __restrict__ C0, float* __restrict__ C1,
    const float* __restrict__ bias0, const float* __restrict__ bias1) {
  const int m0 = blockIdx.y * 128;
  const int n0 = blockIdx.x * 128;
  __shared__ __align__(16) char lds[49152];
  const int t = threadIdx.x;
  const int L = t & 63, w = t >> 6, q = L >> 4, l15 = L & 15;

  const int ar = t >> 1, ah = t & 1;
  const float* aptr = A + (long long)(m0 + ar) * 1024 + ah * 16;
  const int phiA = ((ar >> 1) ^ (ar >> 3)) & 3;
  const int wa0 = ar * 64 + (((2 * ah + 0) ^ phiA) << 4);
  const int wa1 = ar * 64 + (((2 * ah + 1) ^ phiA) << 4);

  int offA0[4], offB0[4];
#pragma unroll
  for (int f = 0; f < 4; ++f) {
    int rowa = ((w & 1) << 6) + (f << 4) + l15;
    offA0[f] = rowa * 64 + ((q ^ (((rowa >> 1) ^ (rowa >> 3)) & 3)) << 4);
    int rowb = ((w >> 1) << 6) + (f << 4) + l15;
    offB0[f] = rowb * 64 + ((q ^ (((rowb >> 1) ^ (rowb >> 3)) & 3)) << 4);
  }

  const int lrow = L >> 2, lchk = L & 3;
  const unsigned short* bsrc[4];
  int bldso[4];
#pragma unroll
  for (int i = 0; i < 4; ++i) {
    int O = ((w << 2) + i) << 10;
    int s2 = O >> 13;
    int r = ((O & 8191) >> 6) + lrow;
    int phi = ((r >> 1) ^ (r >> 3)) & 3;
    bsrc[i] = Bsp + (long long)s2 * bplane + (long long)(n0 + r) * 1024 +
              ((lchk ^ phi) << 3);
    bldso[i] = O;
  }

  f32x4 acc[4][4];
#pragma unroll
  for (int i = 0; i < 4; ++i)
#pragma unroll
    for (int j = 0; j < 4; ++j) acc[i][j] = (f32x4){0.f, 0.f, 0.f, 0.f};

#pragma unroll
  for (int i = 0; i < 4; ++i) gl_lds16(bsrc[i], &lds[16384 + bldso[i]]);
  float4 a0 = *(const float4*)(aptr + 0);
  float4 a1 = *(const float4*)(aptr + 4);
  float4 a2 = *(const float4*)(aptr + 8);
  float4 a3 = *(const float4*)(aptr + 12);

  int cur = 0;
  for (int k0 = 0; k0 < 1024; k0 += 32) {
    {
      float xs[16] = {a0.x, a0.y, a0.z, a0.w, a1.x, a1.y, a1.z, a1.w,
                      a2.x, a2.y, a2.z, a2.w, a3.x, a3.y, a3.z, a3.w};
      split_store16f(xs, lds, 0, wa0, wa1);
    }
    asm volatile("s_waitcnt vmcnt(0) lgkmcnt(0)\n\ts_barrier" ::: "memory");
    if (k0 < 992) {
      a0 = *(const float4*)(aptr + k0 + 32);
      a1 = *(const float4*)(aptr + k0 + 36);
      a2 = *(const float4*)(aptr + k0 + 40);
      a3 = *(const float4*)(aptr + k0 + 44);
      const int bn = 16384 + ((cur ^ 1) << 14);
#pragma unroll
      for (int i = 0; i < 4; ++i)
        gl_lds16(bsrc[i] + k0 + 32, &lds[bn + bldso[i]]);
    }
    const int bb = 16384 + (cur << 14);
    f16x8 af[2][4];
#pragma unroll
    for (int s = 0; s < 2; ++s)
#pragma unroll
      for (int f = 0; f < 4; ++f)
        af[s][f] = *(const f16x8*)&lds[s * 8192 + offA0[f]];
#pragma unroll
    for (int nf = 0; nf < 4; ++nf) {
      f16x8 bh = *(const f16x8*)&lds[bb + offB0[nf]];
      f16x8 bl = *(const f16x8*)&lds[bb + 8192 + offB0[nf]];
      MFMA3(af, bh, bl, acc, nf);
    }
    asm volatile("s_waitcnt lgkmcnt(0)\n\ts_barrier" ::: "memory");
    cur ^= 1;
  }

  const bool isR = (n0 >= 1024);
  float* Co = isR ? C1 : C0;
  const float* bp = isR ? bias1 : bias0;
  const int nc0 = n0 & 1023;
#pragma unroll
  for (int nf = 0; nf < 4; ++nf) {
    int col = nc0 + ((w >> 1) << 6) + (nf << 4) + l15;
    float bz = bp[col];
#pragma unroll
    for (int mf = 0; mf < 4; ++mf) {
#pragma unroll
      for (int r = 0; r < 4; ++r) {
        int row = m0 + ((w & 1) << 6) + (mf << 4) + (q << 2) + r;
        float x = acc[mf][nf][r] + bz;
        if (LEAKY) x = (x > 0.f) ? x : 0.1f * x;
        Co[(long long)row * 1024 + col] = x;
      }
    }
  }
}

// ---------------------------------------------------------------------------
// Batched NT GEMM on MFMA: C[b] = tmpA[b] * rights[b]^T + rowAdd + scal.
// Both operands fp32, split in-kernel to fp16x2. Tile 128x128, grid (2,2,64).
// ---------------------------------------------------------------------------
__global__ __launch_bounds__(256, 3) void gemmnt_mfma_kernel(
    const float* __restrict__ A, const float* __restrict__ B,
    float* __restrict__ C, const float* __restrict__ rowAdd,
    const float* __restrict__ scal) {
  const int bz = blockIdx.z;
  A += (long long)bz * 256 * 1024;
  B += (long long)bz * 256 * 1024;
  C += (long long)bz * 256 * 256;
  const int m0 = blockIdx.y * 128;
  const int n0 = blockIdx.x * 128;
  __shared__ __align__(16) char lds[32768];
  const int t = threadIdx.x;
  const int L = t & 63, w = t >> 6, q = L >> 4, l15 = L & 15;

  const int ar = t >> 1, ah = t & 1;
  const float* aptr = A + (long long)(m0 + ar) * 1024 + ah * 16;
  const float* bptr = B + (long long)(n0 + ar) * 1024 + ah * 16;
  const int phiA = ((ar >> 1) ^ (ar >> 3)) & 3;
  const int wa0 = ar * 64 + (((2 * ah + 0) ^ phiA) << 4);
  const int wa1 = ar * 64 + (((2 * ah + 1) ^ phiA) << 4);

  int offA0[4], offB0[4];
#pragma unroll
  for (int f = 0; f < 4; ++f) {
    int rowa = ((w & 1) << 6) + (f << 4) + l15;
    offA0[f] = rowa * 64 + ((q ^ (((rowa >> 1) ^ (rowa >> 3)) & 3)) << 4);
    int rowb = ((w >> 1) << 6) + (f << 4) + l15;
    offB0[f] =
        16384 + rowb * 64 + ((q ^ (((rowb >> 1) ^ (rowb >> 3)) & 3)) << 4);
  }

  f32x4 acc[4][4];
#pragma unroll
  for (int i = 0; i < 4; ++i)
#pragma unroll
    for (int j = 0; j < 4; ++j) acc[i][j] = (f32x4){0.f, 0.f, 0.f, 0.f};

  float4 a0 = *(const float4*)(aptr + 0);
  float4 a1 = *(const float4*)(aptr + 4);
  float4 a2 = *(const float4*)(aptr + 8);
  float4 a3 = *(const float4*)(aptr + 12);
  float4 b0 = *(const float4*)(bptr + 0);
  float4 b1 = *(const float4*)(bptr + 4);
  float4 b2 = *(const float4*)(bptr + 8);
  float4 b3 = *(const float4*)(bptr + 12);

  for (int k0 = 0; k0 < 1024; k0 += 32) {
    {
      float xs[16] = {a0.x, a0.y, a0.z, a0.w, a1.x, a1.y, a1.z, a1.w,
                      a2.x, a2.y, a2.z, a2.w, a3.x, a3.y, a3.z, a3.w};
      split_store16f(xs, lds, 0, wa0, wa1);
      float ys[16] = {b0.x, b0.y, b0.z, b0.w, b1.x, b1.y, b1.z, b1.w,
                      b2.x, b2.y, b2.z, b2.w, b3.x, b3.y, b3.z, b3.w};
      split_store16f(ys, lds, 16384, wa0, wa1);
    }
    asm volatile("s_waitcnt lgkmcnt(0)\n\ts_barrier" ::: "memory");
    if (k0 < 992) {
      a0 = *(const float4*)(aptr + k0 + 32);
      a1 = *(const float4*)(aptr + k0 + 36);
      a2 = *(const float4*)(aptr + k0 + 40);
      a3 = *(const float4*)(aptr + k0 + 44);
      b0 = *(const float4*)(bptr + k0 + 32);
      b1 = *(const float4*)(bptr + k0 + 36);
      b2 = *(const float4*)(bptr + k0 + 40);
      b3 = *(const float4*)(bptr + k0 + 44);
    }
    f16x8 af[2][4];
#pragma unroll
    for (int s = 0; s < 2; ++s)
#pragma unroll
      for (int f = 0; f < 4; ++f)
        af[s][f] = *(const f16x8*)&lds[s * 8192 + offA0[f]];
#pragma unroll
    for (int nf = 0; nf < 4; ++nf) {
      f16x8 bh = *(const f16x8*)&lds[offB0[nf]];
      f16x8 bl = *(const f16x8*)&lds[8192 + offB0[nf]];
      MFMA3(af, bh, bl, acc, nf);
    }
    asm volatile("s_waitcnt lgkmcnt(0)\n\ts_barrier" ::: "memory");
  }

  const float sc_add = scal[0];
#pragma unroll
  for (int mf = 0; mf < 4; ++mf) {
#pragma unroll
    for (int r = 0; r < 4; ++r) {
      int row = m0 + ((w & 1) << 6) + (mf << 4) + (q << 2) + r;
      float radd = sc_add + rowAdd[(long long)bz * 256 + row];
#pragma unroll
      for (int nf = 0; nf < 4; ++nf) {
        int col = n0 + ((w >> 1) << 6) + (nf << 4) + l15;
        C[(long long)row * 256 + col] = acc[mf][nf][r] + radd;
      }
    }
  }
}

// ---------------------------------------------------------------------------
// tmpb[i] = dot(lefts[i,:], Wbil[0:H, H]) + Wbil[H,H].  One wave per row.
// ---------------------------------------------------------------------------
__global__ __launch_bounds__(64) void colvec_kernel(
    const float* __restrict__ lefts, const float* __restrict__ bcol,
    const float* __restrict__ corner, float* __restrict__ tmpb) {
  int row = blockIdx.x;
  int lane = threadIdx.x;
  const float* a = lefts + (long long)row * Hh;
  float s = 0.f;
#pragma unroll
  for (int h = lane; h < Hh; h += 64) s = fmaf(a[h], bcol[h], s);
#pragma unroll
  for (int off = 32; off > 0; off >>= 1) s += __shfl_down(s, off, 64);
  if (lane == 0) tmpb[row] = s + corner[0];
}

// ---------------------------------------------------------------------------
// CKY + backtrack. One block per batch, 1024 threads. Chart in LDS, packed
// triangular diag-major. EIGHT diagonals per barrier (round 14, unchanged).
// ---------------------------------------------------------------------------
__global__ __launch_bounds__(1024) void cky_kernel(
    const float* __restrict__ scores,  // [64][256][256]
    uint8_t* __restrict__ Sws,         // [64][32896] packed triangular
    int* __restrict__ out)             // [2][64][256] int32
{
  const int b = blockIdx.x;
  const int t = threadIdx.x;
  const int n = Ss;
  const float* sc = scores + (long long)b * n * n;
  uint8_t* SP = Sws + (long long)b * 32896;

  __shared__ float Dch[32896];
  __shared__ float pv[2][2048];
  __shared__ uint8_t pmv[2][2048];
  __shared__ int stk[256];

  // offsets of tiny diags 0..15
  const int offT[16] = {0,    256,  511,  765,  1018, 1270, 1521, 1771,
                        2020, 2268, 2515, 2761, 3006, 3250, 3493, 3735};

  if (t < n) {
    out[b * n + t] = 0;
    out[Bb * n + b * n + t] = 0;
    Dch[t] = 0.f;  // diag 0
  }
  // s=2 reads pv[1]: its partial range is empty -> -inf sentinel
  pv[1][t] = -3.0e38f;
  pv[1][t + 1024] = -3.0e38f;

  // prologue score prefetch (diags 1..15 at cell t, clamped addresses)
  float PS[16];
  PS[0] = 0.f;
#pragma unroll
  for (int w = 1; w <= 15; ++w) {
    int ic = t;
    if (ic > 255 - w) ic = 255 - w;
    PS[w] = sc[ic * 257 + w];
  }
  asm volatile("s_waitcnt lgkmcnt(0)\n\ts_barrier" ::: "memory");

  // prologue: diags 1..15, one barrier each (generic ascending m-scan,
  // strict > = first-max)
#pragma unroll
  for (int w = 1; w <= 15; ++w) {
    if (t < 256 - w) {
      float bb = Dch[offT[w - 1] + t + 1];  // m=0: 0 + right
      int bm = 0;
#pragma unroll
      for (int m = 1; m < 15; ++m) {
        if (m >= w) break;
        float c = Dch[offT[m] + t] + Dch[offT[w - 1 - m] + t + m + 1];
        if (c > bb) { bb = c; bm = m; }
      }
      Dch[offT[w] + t] = PS[w] + bb;
      SP[offT[w] + t] = (uint8_t)bm;
    }
    asm volatile("s_waitcnt lgkmcnt(0)\n\ts_barrier" ::: "memory");
  }

  // (b): partials for superstep s+1 (8 diags, base W0b+8).
  // Covers m in [jb+8, W0b-1]; all spans are diags <= W0b-1 (>= 1 barrier
  // old when consumed). Slot = jb*256 + cell (RA) or jb*256+gb*128+cell.
  auto run_b = [&](int W0b, int pbuf) {
    const int cnv = n - W0b - 8;  // consumer's nv1
    int jb, gb, u, delta;
    if (cnv > 128) {  // RA: T=128, 1 group/diag, slices (u, u+128)
      jb = 7 - (t >> 7);
      gb = 0;
      u = t & 127;
      delta = 128;
    } else {  // RB/RC: T=64, 2 groups/diag
      const int wid = t >> 6;
      jb = 7 - (wid >> 1);
      gb = wid & 1;
      u = t & 63;
      delta = (cnv > 64) ? 64 : 0;
    }
    const int Wb = W0b + 8 + jb;
    const int nvb = n - Wb;
    int cnt = W0b - jb - 8;
    if (cnt < 0) cnt = 0;
    const int mlo = jb + 8;
    int ml, mh;
    if (cnv > 128) {
      ml = mlo;
      mh = mlo + cnt;
    } else {
      const int per = (cnt + 1) >> 1;
      ml = mlo + gb * per;
      mh = mlo + cnt;
      int e = ml + per;
      if (e < mh) mh = e;
    }
    float b0 = -3.0e38f, b1 = -3.0e38f;
    int m0i = ml, m1i = ml;
    if (u < nvb && ml < mh) {
      int al = ml * n - ((ml * (ml - 1)) >> 1) + u;
      const int kr = Wb - 1 - ml;
      int ar = kr * n - ((kr * (kr - 1)) >> 1) + u + ml + 1;
      int dl = n - ml;
      int dr = n - Wb + ml + 1;
      if (delta) {
#pragma unroll 4
        for (int m = ml; m < mh; ++m) {
          float l0 = Dch[al], l1 = Dch[al + delta];  // -> ds_read2_b32
          float r0 = Dch[ar], r1 = Dch[ar + delta];  // -> ds_read2_b32
          float c0 = l0 + r0, c1 = l1 + r1;
          if (c0 > b0) { b0 = c0; m0i = m; }  // strict > = first max
          if (c1 > b1) { b1 = c1; m1i = m; }
          al += dl;
          ar -= dr;
          --dl;
          ++dr;
        }
      } else {
#pragma unroll 8
        for (int m = ml; m < mh; ++m) {
          float c = Dch[al] + Dch[ar];
          if (c > b0) { b0 = c; m0i = m; }
          al += dl;
          ar -= dr;
          --dl;
          ++dr;
        }
      }
    }
    const int slot = jb * 256 + gb * 128 + u;
    pv[pbuf][slot] = b0;
    pmv[pbuf][slot] = (uint8_t)m0i;
    if (delta) {
      pv[pbuf][slot + delta] = b1;
      pmv[pbuf][slot + delta] = (uint8_t)m1i;
    }
  };

  // (a)-band geometry: wave wv covers cells 57*wv + lane (7-lane overlap)
  const int wv = t >> 6, lane = t & 63;
  const int tcell = 57 * wv + lane;

  // seed scores for s=2 (diags 16..23)
  float scA[8];
#pragma unroll
  for (int j = 0; j < 8; ++j) {
    const int Wn = 16 + j;
    int ic = tcell;
    if (ic > 255 - Wn) ic = 255 - Wn;
    scA[j] = sc[ic * 257 + Wn];
  }

  for (int s = 2; s <= 31; ++s) {
    const int W0 = 8 * s;
    const int nv1 = n - W0;
    const int pb = s & 1, po = pb ^ 1;
    const int nb = (nv1 + 56) / 57;

    // prefetch next superstep's scores (diags W0+8..W0+15)
    float P8[8] = {0.f, 0.f, 0.f, 0.f, 0.f, 0.f, 0.f, 0.f};
    if (s < 31 && wv < nb) {
#pragma unroll
      for (int j = 0; j < 8; ++j) {
        const int Wn = W0 + 8 + j;
        int ic = tcell;
        if (ic > 255 - Wn) ic = 255 - Wn;
        if (ic < 0) ic = 0;
        P8[j] = sc[ic * 257 + Wn];
      }
    }

    // ---- (a): finalize diags W0..W0+7 ----
    if (wv < nb) {
      const int tc = (tcell < nv1) ? tcell : (nv1 - 1);  // clamped (safe)
      const float* pvo = pv[po];
      const uint8_t* pmo = pmv[po];
      const bool RA = (nv1 > 128);
      int offPB[8], offCB[8];
#pragma unroll
      for (int d = 0; d < 8; ++d) {
        const int dg = W0 - 8 + d;
        offPB[d] = dg * 256 - ((dg * (dg - 1)) >> 1);
        const int cg = W0 + d;
        offCB[d] = cg * 256 - ((cg * (cg - 1)) >> 1);
      }
      float VAL[8];
#pragma unroll
      for (int j = 0; j < 8; ++j) {
        const int W = W0 + j;
        float bb;
        int bm = 0;
        // m = 0
        if (j == 0) {
          bb = Dch[offPB[7] + tc + 1];  // 0 + prev-batch diag W0-1
        } else {
          bb = __shfl_down(VAL[j - 1], 1, 64);  // 0 + VAL_{j-1}(c+1)
        }
        // dyn-low m in [1, j-1]
#pragma unroll
        for (int m = 1; m < 8; ++m) {
          if (m >= j) break;
          float c = Dch[offT[m] + tc] + __shfl_down(VAL[j - 1 - m], m + 1, 64);
          if (c > bb) { bb = c; bm = m; }
        }
        // static-low m in [max(j,1), j+7]
#pragma unroll
        for (int m2 = 0; m2 < 8; ++m2) {
          const int m = j + m2;
          if (m == 0) continue;  // handled as m=0
          float c = Dch[offT[m] + tc] + Dch[offPB[7 - m2] + tc + m + 1];
          if (c > bb) { bb = c; bm = m; }
        }
        // partials [j+8, W0-9]
        if (RA) {
          const int sl = j * 256 + tc;
          float x = pvo[sl];
          if (x > bb) { bb = x; bm = pmo[sl]; }
        } else {
#pragma unroll
          for (int g = 0; g < 2; ++g) {
            const int sl = j * 256 + g * 128 + tc;
            float x = pvo[sl];
            if (x > bb) { bb = x; bm = pmo[sl]; }
          }
        }
        // static-high m = W0-8+d, d = 0..7 (ascending)
#pragma unroll
        for (int d = 0; d < 8; ++d) {
          const int m = W0 - 8 + d;
          const int rp = j + 7 - d;  // right tiny diag
          float right = (rp == 0) ? 0.f : Dch[offT[rp] + tc + W - rp];
          float c = Dch[offPB[d] + tc] + right;
          if (c > bb) { bb = c; bm = m; }
        }
        // dyn-high m = W0+e, e in [0, j-1]
#pragma unroll
        for (int e = 0; e < 8; ++e) {
          if (e >= j) break;
          const int rp = j - 1 - e;
          float right = (rp == 0) ? 0.f : Dch[offT[rp] + tc + W - rp];
          float c = VAL[e] + right;
          if (c > bb) { bb = c; bm = W0 + e; }
        }
        VAL[j] = scA[j] + bb;
        if (lane <= 63 - j && tcell < nv1 - j) {
          Dch[offCB[j] + tcell] = VAL[j];
          SP[offCB[j] + tcell] = (uint8_t)bm;
        }
      }
    }

    // ---- (b): partials for superstep s+1 (diags W0+8..W0+15) ----
    if (s < 31) run_b(W0, pb);

    asm volatile("s_waitcnt lgkmcnt(0)\n\ts_barrier" ::: "memory");
#pragma unroll
    for (int j = 0; j < 8; ++j) scA[j] = P8[j];
  }

  // Drain all SP stores (whole loop's worth) once, then barrier.
  asm volatile("s_waitcnt vmcnt(0) lgkmcnt(0)\n\ts_barrier" ::: "memory");
  uint8_t* spl = (uint8_t*)Dch;
  for (int idx = t; idx < 32896; idx += 1024) spl[idx] = SP[idx];
  asm volatile("s_waitcnt vmcnt(0) lgkmcnt(0)\n\ts_barrier" ::: "memory");
  if (t == 0) {
    int top = 0;
    stk[top++] = (0 << 16) | (n - 1);
    int cnt = 0;
    for (int step = 0; step < n - 1; ++step) {
      if (top > 0) {
        int ij = stk[--top];
        int ii = ij >> 16, jj = ij & 0xffff;
        out[b * n + cnt] = ii;
        out[Bb * n + b * n + cnt] = jj;
        ++cnt;
        int k = jj - ii;
        int s2 = ii + (int)spl[k * n - ((k * (k - 1)) >> 1) + ii];
        stk[top] = (ii << 16) | s2;
        if (s2 > ii) ++top;
        stk[top] = ((s2 + 1) << 16) | jj;
        if (jj > s2 + 1) ++top;
      }
    }
  }
}

// ---------------------------------------------------------------------------
// Launch
// ---------------------------------------------------------------------------
extern "C" void kernel_launch(void* const* d_in, const int* in_sizes, int n_in,
                              void* d_out, int out_size, void* d_ws,
                              size_t ws_size, hipStream_t stream) {
  const float* X = (const float*)d_in[0];     // [64,256,1024]
  const float* Wl = (const float*)d_in[2];    // [1024,1024]
  const float* bl = (const float*)d_in[3];    // [1024]
  const float* Wr = (const float*)d_in[4];
  const float* br = (const float*)d_in[5];
  const float* Wbil = (const float*)d_in[6];  // [1025,1025]
  const float* bbil = (const float*)d_in[7];  // scalar
  int* out = (int*)d_out;

  // workspace layout
  float* ws = (float*)d_ws;
  float* lefts = ws;                          // 16777216 f
  float* rights = lefts + 16777216;           // 16777216 f
  float* tmpA = rights + 16777216;            // 16777216 f
  float* scoresP = tmpA + 16777216;           // 4194304 f
  float* tmpb = scoresP + 4194304;            // 16384 f
  float* browp = tmpb + 16384;                // 1024 f
  float* bcolp = browp + 1024;                // 1024 f
  float* cornerp = bcolp + 1024;              // 4 f
  unsigned short* Wlrt = (unsigned short*)(cornerp + 4);  // 2 x 2M fp16
  unsigned short* Wct = Wlrt + 2LL * 2097152;             // 2 x 1M fp16
  uint8_t* SPp = (uint8_t*)(Wct + 2LL * 1048576);         // 64x32896 u8

  // weight splits (+ Wbil bias vectors) — coalesced LDS-transpose version
  splitw_kernel<<<dim3(16, 16), 256, 0, stream>>>(Wl, 1024, Wlrt, 2097152);
  splitw_kernel<<<dim3(16, 16), 256, 0, stream>>>(Wr, 1024, Wlrt + 1048576,
                                                  2097152);
  splitw_kernel<<<dim3(16, 16), 256, 0, stream>>>(Wbil, 1025, Wct, 1048576);
  bilvec_kernel<<<dim3(4), 256, 0, stream>>>(Wbil, browp, bcolp, cornerp);

  // fused lefts|rights GEMM: N=2048
  dim3 gLR(16, 128);
  gemm_mfma_kernel<true><<<gLR, 256, 0, stream>>>(X, Wlrt, 2097152LL, lefts,
                                                  rights, bl, br);

  colvec_kernel<<<dim3(16384), 64, 0, stream>>>(lefts, bcolp, cornerp, tmpb);

  dim3 gA(8, 128);
  gemm_mfma_kernel<false><<<gA, 256, 0, stream>>>(lefts, Wct, 1048576LL, tmpA,
                                                  tmpA, browp, browp);

  dim3 g3(2, 2, 64);
  gemmnt_mfma_kernel<<<g3, 256, 0, stream>>>(tmpA, rights, scoresP, tmpb,
                                             bbil);

  cky_kernel<<<dim3(Bb), dim3(1024), 0, stream>>>(scoresP, SPp, out);
}